// Round 17
// baseline (60.781 us; speedup 1.0000x reference)
//
#include <hip/hip_runtime.h>
#include <math.h>

typedef short bfx8 __attribute__((ext_vector_type(8)));
typedef short bfx4 __attribute__((ext_vector_type(4)));
typedef float fx4  __attribute__((ext_vector_type(4)));
typedef unsigned int ux2 __attribute__((ext_vector_type(2)));
typedef unsigned int ux4v __attribute__((ext_vector_type(4)));

__device__ __forceinline__ unsigned short f2bf(float f) {
    unsigned int u = __builtin_bit_cast(unsigned int, f);
    u += 0x7FFFu + ((u >> 16) & 1u);        // round-to-nearest-even
    return (unsigned short)(u >> 16);
}
__device__ __forceinline__ float bf2f(unsigned short s) {
    unsigned int u = ((unsigned int)s) << 16;
    return __builtin_bit_cast(float, u);
}
__device__ __forceinline__ unsigned int cvtpk(float a, float b) {
    unsigned int d;
    asm("v_cvt_pk_bf16_f32 %0, %1, %2" : "=v"(d) : "v"(a), "v"(b));
    return d;   // lo = bf16(a), hi = bf16(b)
}

// ---------- Wt prep: wt[192][1024] bf16 = [Wq*(2^-5*log2e); Wk; Wv]^T ----------
__global__ __launch_bounds__(256) void wt_prep(const float* __restrict__ Wq,
                                               const float* __restrict__ Wk,
                                               const float* __restrict__ Wv,
                                               unsigned short* __restrict__ wt)
{
    const int k0  = blockIdx.x * 64;
    const int mat = blockIdx.y;
    const float* W = (mat == 0) ? Wq : ((mat == 1) ? Wk : Wv);
    const float scale = (mat == 0) ? (0.03125f * 1.4426950408889634f) : 1.0f;
    __shared__ unsigned short Ls[64 * 68];
    const int t = threadIdx.x;
    #pragma unroll
    for (int i = 0; i < 4; ++i) {
        int idx4 = t + 256 * i;
        int r = idx4 >> 4, c4 = idx4 & 15;
        float4 v = *(const float4*)&W[(size_t)(k0 + r) * 64 + c4 * 4];
        Ls[r * 68 + c4 * 4 + 0] = f2bf(v.x * scale);
        Ls[r * 68 + c4 * 4 + 1] = f2bf(v.y * scale);
        Ls[r * 68 + c4 * 4 + 2] = f2bf(v.z * scale);
        Ls[r * 68 + c4 * 4 + 3] = f2bf(v.w * scale);
    }
    __syncthreads();
    #pragma unroll
    for (int i = 0; i < 2; ++i) {
        int u = t + 256 * i;
        int n = u >> 3, kc = u & 7;
        bfx8 o;
        #pragma unroll
        for (int j = 0; j < 8; ++j) o[j] = (short)Ls[(kc * 8 + j) * 68 + n];
        *(bfx8*)&wt[(size_t)(mat * 64 + n) * 1024 + k0 + kc * 8] = o;
    }
}

// ---------- QKV: BM=32, grid 512, MFMA bf16 (R12 verbatim) ----------
__global__ __launch_bounds__(256) void qkv_mfma(
    const float* __restrict__ x, const unsigned short* __restrict__ wt,
    unsigned short* __restrict__ qb, unsigned short* __restrict__ kb,
    unsigned short* __restrict__ vt)
{
    __shared__ alignas(16) char smem[57344];
    const int t = threadIdx.x;
    const int w = t >> 6, l = t & 63, g = l >> 4, li = l & 15;
    const int m0 = blockIdx.x * 32;
    const int rh  = (w & 1) * 16;
    const int nb0 = (w >> 1) * 6;

    fx4 acc[6];
    #pragma unroll
    for (int i = 0; i < 6; ++i) acc[i] = (fx4){0.f, 0.f, 0.f, 0.f};

    float4 xr[2];

    const unsigned short* wSrc[6];
    #pragma unroll
    for (int i = 0; i < 6; ++i) {
        int s = w * 6144 + i * 1024 + l * 16;
        int n = s >> 7, c = ((s >> 4) & 7) ^ (n & 7);
        wSrc[i] = wt + (size_t)n * 1024 + c * 8;
    }

#define QKV_DMA_W(K0, BI) do { \
    _Pragma("unroll") for (int i_ = 0; i_ < 6; ++i_) \
        __builtin_amdgcn_global_load_lds( \
            (const __attribute__((address_space(1))) void*)(wSrc[i_] + (K0)), \
            (__attribute__((address_space(3))) void*)(smem + 8192 + (BI) * 24576 + w * 6144 + i_ * 1024), \
            16, 0, 0); \
} while (0)

#define QKV_LOAD_X(K0) do { \
    _Pragma("unroll") for (int i_ = 0; i_ < 2; ++i_) { int idx4 = t + 256 * i_; int r_ = idx4 >> 4, c4 = idx4 & 15; \
        xr[i_] = *(const float4*)&x[(size_t)(m0 + r_) * 1024 + (K0) + c4 * 4]; } \
} while (0)

#define QKV_STORE_X(BI) do { \
    char* xb_ = smem + (BI) * 4096; \
    _Pragma("unroll") for (int i_ = 0; i_ < 2; ++i_) { int idx4 = t + 256 * i_; int r_ = idx4 >> 4, c4 = idx4 & 15; \
        ux2 u_; u_[0] = cvtpk(xr[i_].x, xr[i_].y); u_[1] = cvtpk(xr[i_].z, xr[i_].w); \
        *(ux2*)(xb_ + ((r_ * 128 + c4 * 8) ^ ((r_ & 7) << 4))) = u_; } \
} while (0)

    QKV_LOAD_X(0); QKV_STORE_X(0); QKV_DMA_W(0, 0);
    __syncthreads();

    for (int ch = 0; ch < 16; ++ch) {
        if (ch + 1 < 16) { QKV_DMA_W((ch + 1) * 64, (ch + 1) & 1); QKV_LOAD_X((ch + 1) * 64); }
        char* xb = smem + (ch & 1) * 4096;
        char* wb = smem + 8192 + (ch & 1) * 24576;
        const int arow = rh + li;
        #pragma unroll
        for (int kk = 0; kk < 2; ++kk) {
            bfx8 af = *(bfx8*)(xb + ((arow * 128 + kk * 64 + g * 16) ^ ((arow & 7) << 4)));
            #pragma unroll
            for (int nb = 0; nb < 6; ++nb) {
                int nrow = (nb0 + nb) * 16 + li;
                bfx8 bf = *(bfx8*)(wb + ((nrow * 128 + kk * 64 + g * 16) ^ ((nrow & 7) << 4)));
                acc[nb] = __builtin_amdgcn_mfma_f32_16x16x32_bf16(af, bf, acc[nb], 0, 0, 0);
            }
        }
        if (ch + 1 < 16) QKV_STORE_X((ch + 1) & 1);
        __syncthreads();
    }

    const int mrow = m0 + rh + g * 4;
    #pragma unroll
    for (int nb = 0; nb < 6; ++nb) {
        const int nbg = nb0 + nb;
        if (nbg < 4) {
            #pragma unroll
            for (int r = 0; r < 4; ++r)
                qb[(size_t)(mrow + r) * 64 + nbg * 16 + li] = f2bf(acc[nb][r]);
        } else if (nbg < 8) {
            #pragma unroll
            for (int r = 0; r < 4; ++r)
                kb[(size_t)(mrow + r) * 64 + (nbg - 4) * 16 + li] = f2bf(acc[nb][r]);
        }
    }

    __syncthreads();
    unsigned short* Vt = (unsigned short*)smem;      // [64 d][40] padded
    #pragma unroll
    for (int nb = 0; nb < 6; ++nb) {
        const int nbg = nb0 + nb;
        if (nbg >= 8) {
            #pragma unroll
            for (int r = 0; r < 4; ++r)   // perm: u=16h+4g+r -> g*8+4h+r  (h = rh/16)
                Vt[((nbg - 8) * 16 + li) * 40 + g * 8 + (rh >> 2) + r] = f2bf(acc[nb][r]);
        }
    }
    __syncthreads();
    const int bb = m0 >> 12, mt = m0 & 4095;
    {
        int d = t >> 2, c = t & 3;
        *(bfx8*)&vt[((size_t)(bb * 64 + d)) * 4096 + mt + c * 8] = *(bfx8*)&Vt[d * 40 + c * 8];
    }
}

// ---------- attention: 128q tile, 8 waves, 64kv chunks, counted-vmcnt ----------
// grid 576 = 4b x 144 segs (512 kv each); >=512 blocks co-resident.
// waves: qsub=w&3 (32q of 128), par=w>>2 (32kv of 64). Per-wave code = R12.
__global__ __launch_bounds__(512, 4) void attn_mfma(
    const unsigned short* __restrict__ qb, const unsigned short* __restrict__ kb,
    const unsigned short* __restrict__ vt,
    unsigned short* __restrict__ pO, float* __restrict__ pml)
{
    __shared__ alignas(16) char smem[36864]; // K@0,8192 V@16384,24576 | epi: Osh@0 32KB, lsh@32768 4KB
    const int t = threadIdx.x;
    const int w = t >> 6, l = t & 63, g = l >> 4, li = l & 15;
    const int bx = blockIdx.x;

    const int b = bx & 3;
    const int j = bx >> 2;                    // 0..143
    int qt, seg, nch;
    if (j < 120) {                            // full 8-chunk segments
        int a = 0;
        #pragma unroll
        for (int aa = 1; aa <= 7; ++aa) if (j >= aa * (2 * aa - 1)) a = aa;
        const int local = j - a * (2 * a - 1);   // 0..4a
        int r;
        if      (local <     a) { r = 0; seg = local; }
        else if (local < 2 * a) { r = 1; seg = local - a; }
        else if (local < 3 * a) { r = 2; seg = local - 2 * a; }
        else                    { r = 3; seg = local - 3 * a; }
        qt = 4 * a + r; nch = 8;
    } else {                                  // partial diagonal segs, heavy first
        const int jd = j - 120;               // 0..23
        const int grp = jd >> 3, a = jd & 7;
        const int r = 2 - grp;
        qt = 4 * a + r; seg = a; nch = 2 * r + 2;
    }
    const int qbase = qt * 128;
    const int kvb = seg * 512;
    const int qsub = w & 3, par = w >> 2;
    const int qmax_w = qbase + qsub * 32 + 31;
    const int a2 = qt >> 2, r2 = qt & 3;
    const int slot = b * 144 + (a2 + 1) * (2 * a2 + r2) + seg;

    const unsigned short* Qg = qb + (size_t)b * 4096 * 64;
    const unsigned short* Kg = kb + (size_t)b * 4096 * 64;
    const unsigned short* Vg = vt + (size_t)b * 64 * 4096;

    // per-lane inverse-swizzled K/V DMA sources (T21); wave stages 1KB of each
    const unsigned short* kSrc;
    const unsigned short* vSrc;
    {
        int ofs = w * 1024 + l * 16;
        int row = ofs >> 7, sl = (ofs >> 4) & 7;
        int c = sl ^ (row & 7);
        kSrc = Kg + (size_t)row * 64 + c * 8;
        vSrc = Vg + (size_t)row * 4096 + c * 8;
    }

#define ATT_DMA(CB, BI) do { \
    __builtin_amdgcn_global_load_lds( \
        (const __attribute__((address_space(1))) void*)(kSrc + (size_t)(CB) * 64), \
        (__attribute__((address_space(3))) void*)(smem + (BI) * 8192 + w * 1024), 16, 0, 0); \
    __builtin_amdgcn_global_load_lds( \
        (const __attribute__((address_space(1))) void*)(vSrc + (CB)), \
        (__attribute__((address_space(3))) void*)(smem + 16384 + (BI) * 8192 + w * 1024), 16, 0, 0); \
} while (0)

    // Q fragments direct from global (L2-resident)
    bfx8 qf[2][2];
    #pragma unroll
    for (int f = 0; f < 2; ++f)
        #pragma unroll
        for (int h = 0; h < 2; ++h)
            qf[f][h] = *(const bfx8*)&Qg[(size_t)(qbase + qsub * 32 + f * 16 + li) * 64 + h * 32 + g * 8];

    // depth-2 prefetch prologue
    ATT_DMA(kvb, 0);
    if (nch > 1) ATT_DMA(kvb + 64, 1);

    fx4 o[4][2];
    #pragma unroll
    for (int i = 0; i < 4; ++i)
        #pragma unroll
        for (int f = 0; f < 2; ++f) o[i][f] = (fx4){0.f, 0.f, 0.f, 0.f};
    float lsum[2] = {0.f, 0.f};

    for (int ch = 0; ch < nch; ++ch) {
        // wait for OWN chunk-ch DMA only; chunk-(ch+1)'s 2 stay in flight (T4)
        if (ch < nch - 1) { asm volatile("s_waitcnt vmcnt(2)" ::: "memory"); }
        else              { asm volatile("s_waitcnt vmcnt(0)" ::: "memory"); }
        __builtin_amdgcn_sched_barrier(0);
        __builtin_amdgcn_s_barrier();            // all waves' chunk-ch data landed
        asm volatile("" ::: "memory");

        char* ks = smem + (ch & 1) * 8192;
        char* vs = smem + 16384 + (ch & 1) * 8192;
        const int cb = kvb + (ch << 6);
        const int sub = cb + par * 32;
        if (sub <= qmax_w) {                     // wave-uniform causal skip
            fx4 s[2][2];
            #pragma unroll
            for (int st = 0; st < 2; ++st)
                #pragma unroll
                for (int f = 0; f < 2; ++f) s[st][f] = (fx4){0.f, 0.f, 0.f, 0.f};
            __builtin_amdgcn_s_setprio(1);
            #pragma unroll
            for (int st = 0; st < 2; ++st) {
                const int krow = par * 32 + st * 16 + li;
                const int sw = (krow & 7) << 4;
                bfx8 kf0 = *(bfx8*)(ks + ((krow * 128 + g * 16) ^ sw));
                bfx8 kf1 = *(bfx8*)(ks + ((krow * 128 + 64 + g * 16) ^ sw));
                #pragma unroll
                for (int f = 0; f < 2; ++f) {
                    s[st][f] = __builtin_amdgcn_mfma_f32_16x16x32_bf16(kf0, qf[f][0], s[st][f], 0, 0, 0);
                    s[st][f] = __builtin_amdgcn_mfma_f32_16x16x32_bf16(kf1, qf[f][1], s[st][f], 0, 0, 0);
                }
            }
            __builtin_amdgcn_s_setprio(0);

            // fixed-max softmax: P = exp2(s); pack via v_cvt_pk_bf16_f32
            bfx8 pf[2];
            #pragma unroll
            for (int f = 0; f < 2; ++f) {
                const int qmin_f = qbase + qsub * 32 + f * 16;
                float p[8];
                if (sub + 31 > qmin_f) {           // diagonal: apply causal mask
                    #pragma unroll
                    for (int st = 0; st < 2; ++st)
                        #pragma unroll
                        for (int rr = 0; rr < 4; ++rr) {
                            int kv = sub + st * 16 + 4 * g + rr;
                            p[st * 4 + rr] = (kv <= qmin_f + li) ? s[st][f][rr] : -1e30f;
                        }
                } else {
                    #pragma unroll
                    for (int st = 0; st < 2; ++st)
                        #pragma unroll
                        for (int rr = 0; rr < 4; ++rr) p[st * 4 + rr] = s[st][f][rr];
                }
                #pragma unroll
                for (int e = 0; e < 8; ++e) p[e] = exp2f(p[e]);
                lsum[f] += ((p[0]+p[1])+(p[2]+p[3])) + ((p[4]+p[5])+(p[6]+p[7]));
                ux4v pu;
                pu[0] = cvtpk(p[0], p[1]); pu[1] = cvtpk(p[2], p[3]);
                pu[2] = cvtpk(p[4], p[5]); pu[3] = cvtpk(p[6], p[7]);
                pf[f] = __builtin_bit_cast(bfx8, pu);
            }

            __builtin_amdgcn_s_setprio(1);
            #pragma unroll
            for (int dblk = 0; dblk < 4; ++dblk) {
                const int dr = dblk * 16 + li;
                // perm-baked V: one contiguous bfx8 = the exact PV A-fragment
                bfx8 vf = *(bfx8*)(vs + ((dr * 128 + par * 64 + g * 16) ^ ((dr & 7) << 4)));
                #pragma unroll
                for (int f = 0; f < 2; ++f)
                    o[dblk][f] = __builtin_amdgcn_mfma_f32_16x16x32_bf16(vf, pf[f], o[dblk][f], 0, 0, 0);
            }
            __builtin_amdgcn_s_setprio(0);
        }

        __builtin_amdgcn_s_barrier();            // all waves done reading buf[ch&1]
        asm volatile("" ::: "memory");
        if (ch + 2 < nch) ATT_DMA(kvb + ((ch + 2) << 6), ch & 1);  // refill freed buffer
    }
    asm volatile("" ::: "memory");

    // ---- epilogue phase A: par=1 waves publish O to LDS; all publish lsum ----
    float* Osh = (float*)smem;                 // [128 q][64 d] fp32 = 32KB
    float* lsh = (float*)(smem + 32768);       // [8 w][2 f][4 g][16 li] = 4KB
    #pragma unroll
    for (int f = 0; f < 2; ++f)
        lsh[((w * 2 + f) * 4 + g) * 16 + li] = lsum[f];
    if (par == 1) {
        #pragma unroll
        for (int dblk = 0; dblk < 4; ++dblk)
            #pragma unroll
            for (int f = 0; f < 2; ++f)
                #pragma unroll
                for (int r = 0; r < 4; ++r)
                    Osh[(qsub * 32 + f * 16 + li) * 64 + dblk * 16 + g * 4 + r] = o[dblk][f][r];
    }
    __syncthreads();

    // ---- phase B: par=0 waves combine in-place + write L ----
    if (par == 0) {
        #pragma unroll
        for (int f = 0; f < 2; ++f) {
            const int qrow = qsub * 32 + f * 16 + li;
            #pragma unroll
            for (int dblk = 0; dblk < 4; ++dblk)
                #pragma unroll
                for (int r = 0; r < 4; ++r)
                    Osh[qrow * 64 + dblk * 16 + g * 4 + r] += o[dblk][f][r];
            if (g == 0) {
                float L = 0.f;
                #pragma unroll
                for (int p2 = 0; p2 < 2; ++p2)
                    #pragma unroll
                    for (int gg = 0; gg < 4; ++gg)
                        L += lsh[(((p2 * 4 + qsub) * 2 + f) * 4 + gg) * 16 + li];
                pml[(size_t)slot * 128 + qrow] = L;
            }
        }
    }
    __syncthreads();

    // ---- phase C: coalesced bf16 repack to pO (16B/lane) ----
    #pragma unroll
    for (int i = 0; i < 2; ++i) {
        int u = t + 512 * i;                   // 0..1023 bfx8 units
        int q = u >> 3, c = u & 7;
        const float* src = &Osh[q * 64 + c * 8];
        ux4v uo;
        uo[0] = cvtpk(src[0], src[1]); uo[1] = cvtpk(src[2], src[3]);
        uo[2] = cvtpk(src[4], src[5]); uo[3] = cvtpk(src[6], src[7]);
        *(bfx8*)&pO[(size_t)slot * 8192 + q * 64 + c * 8] = __builtin_bit_cast(bfx8, uo);
    }
}

// ---------- merge: sum up to 8 segment partials, normalize, write out ----------
__global__ __launch_bounds__(256) void attn_merge(
    const unsigned short* __restrict__ pO, const float* __restrict__ pml,
    float* __restrict__ out)
{
    const int b = blockIdx.x & 3, qt = blockIdx.x >> 2;   // qt 0..31
    const int a = qt >> 2, r = qt & 3;
    const int nseg = a + 1;
    const int slot0 = b * 144 + (a + 1) * (2 * a + r);
    const int t = threadIdx.x;
    const int q = t >> 1, d0 = (t & 1) * 32;

    float L = 0.f;
    float acc[32];
    #pragma unroll
    for (int jj = 0; jj < 32; ++jj) acc[jj] = 0.f;
    for (int s = 0; s < nseg; ++s) {
        L += pml[(size_t)(slot0 + s) * 128 + q];
        const unsigned short* src = pO + (size_t)(slot0 + s) * 8192 + q * 64 + d0;
        #pragma unroll
        for (int v = 0; v < 4; ++v) {
            bfx8 vv = *(const bfx8*)&src[v * 8];
            #pragma unroll
            for (int jj = 0; jj < 8; ++jj) acc[v * 8 + jj] += bf2f((unsigned short)vv[jj]);
        }
    }
    const float inv = 1.f / L;
    float* orow = out + ((size_t)b * 4096 + qt * 128 + q) * 64 + d0;
    #pragma unroll
    for (int v4 = 0; v4 < 8; ++v4) {
        float4 rv;
        rv.x = acc[v4 * 4 + 0] * inv; rv.y = acc[v4 * 4 + 1] * inv;
        rv.z = acc[v4 * 4 + 2] * inv; rv.w = acc[v4 * 4 + 3] * inv;
        *(float4*)&orow[v4 * 4] = rv;
    }
}

extern "C" void kernel_launch(void* const* d_in, const int* in_sizes, int n_in,
                              void* d_out, int out_size, void* d_ws, size_t ws_size,
                              hipStream_t stream)
{
    // setup_inputs order: x, Wk, Wq, Wv
    const float* x  = (const float*)d_in[0];
    const float* Wk = (const float*)d_in[1];
    const float* Wq = (const float*)d_in[2];
    const float* Wv = (const float*)d_in[3];
    float* outp = (float*)d_out;

    char* ws = (char*)d_ws;
    unsigned short* qbuf = (unsigned short*)(ws);                    // 2MB
    unsigned short* kbuf = (unsigned short*)(ws + 2*1024*1024);      // 2MB
    unsigned short* vtb  = (unsigned short*)(ws + 4*1024*1024);      // 2MB (V^T, perm-baked)
    unsigned short* wtb  = (unsigned short*)(ws + 6*1024*1024);      // 384KB (W^T)
    unsigned short* pO   = (unsigned short*)(ws + 7*1024*1024);      // 576*16KB = 9.2MB
    float*          pml  = (float*)(ws + 17*1024*1024);              // 576*512B = 295KB

    wt_prep<<<dim3(16, 3), 256, 0, stream>>>(Wq, Wk, Wv, wtb);
    qkv_mfma<<<512, 256, 0, stream>>>(x, wtb, qbuf, kbuf, vtb);
    attn_mfma<<<576, 512, 0, stream>>>(qbuf, kbuf, vtb, pO, pml);
    attn_merge<<<128, 256, 0, stream>>>(pO, pml, outp);
}

// Round 18
// 56.365 us; speedup vs baseline: 1.0784x; 1.0784x over previous
//
#include <hip/hip_runtime.h>
#include <math.h>

typedef short bfx8 __attribute__((ext_vector_type(8)));
typedef short bfx4 __attribute__((ext_vector_type(4)));
typedef float fx4  __attribute__((ext_vector_type(4)));
typedef unsigned int ux2 __attribute__((ext_vector_type(2)));
typedef unsigned int ux4v __attribute__((ext_vector_type(4)));

__device__ __forceinline__ unsigned short f2bf(float f) {
    unsigned int u = __builtin_bit_cast(unsigned int, f);
    u += 0x7FFFu + ((u >> 16) & 1u);        // round-to-nearest-even
    return (unsigned short)(u >> 16);
}
__device__ __forceinline__ float bf2f(unsigned short s) {
    unsigned int u = ((unsigned int)s) << 16;
    return __builtin_bit_cast(float, u);
}
__device__ __forceinline__ unsigned int cvtpk(float a, float b) {
    unsigned int d;
    asm("v_cvt_pk_bf16_f32 %0, %1, %2" : "=v"(d) : "v"(a), "v"(b));
    return d;   // lo = bf16(a), hi = bf16(b)
}

// ---------- Wt prep: wt[192][1024] bf16 = [Wq*(2^-5*log2e); Wk; Wv]^T ----------
__global__ __launch_bounds__(256) void wt_prep(const float* __restrict__ Wq,
                                               const float* __restrict__ Wk,
                                               const float* __restrict__ Wv,
                                               unsigned short* __restrict__ wt)
{
    const int k0  = blockIdx.x * 64;
    const int mat = blockIdx.y;
    const float* W = (mat == 0) ? Wq : ((mat == 1) ? Wk : Wv);
    const float scale = (mat == 0) ? (0.03125f * 1.4426950408889634f) : 1.0f;
    __shared__ unsigned short Ls[64 * 68];
    const int t = threadIdx.x;
    #pragma unroll
    for (int i = 0; i < 4; ++i) {
        int idx4 = t + 256 * i;
        int r = idx4 >> 4, c4 = idx4 & 15;
        float4 v = *(const float4*)&W[(size_t)(k0 + r) * 64 + c4 * 4];
        Ls[r * 68 + c4 * 4 + 0] = f2bf(v.x * scale);
        Ls[r * 68 + c4 * 4 + 1] = f2bf(v.y * scale);
        Ls[r * 68 + c4 * 4 + 2] = f2bf(v.z * scale);
        Ls[r * 68 + c4 * 4 + 3] = f2bf(v.w * scale);
    }
    __syncthreads();
    #pragma unroll
    for (int i = 0; i < 2; ++i) {
        int u = t + 256 * i;
        int n = u >> 3, kc = u & 7;
        bfx8 o;
        #pragma unroll
        for (int j = 0; j < 8; ++j) o[j] = (short)Ls[(kc * 8 + j) * 68 + n];
        *(bfx8*)&wt[(size_t)(mat * 64 + n) * 1024 + k0 + kc * 8] = o;
    }
}

// ---------- QKV: BM=32, grid 512, MFMA bf16 (R12 verbatim) ----------
__global__ __launch_bounds__(256) void qkv_mfma(
    const float* __restrict__ x, const unsigned short* __restrict__ wt,
    unsigned short* __restrict__ qb, unsigned short* __restrict__ kb,
    unsigned short* __restrict__ vt)
{
    __shared__ alignas(16) char smem[57344];
    const int t = threadIdx.x;
    const int w = t >> 6, l = t & 63, g = l >> 4, li = l & 15;
    const int m0 = blockIdx.x * 32;
    const int rh  = (w & 1) * 16;
    const int nb0 = (w >> 1) * 6;

    fx4 acc[6];
    #pragma unroll
    for (int i = 0; i < 6; ++i) acc[i] = (fx4){0.f, 0.f, 0.f, 0.f};

    float4 xr[2];

    const unsigned short* wSrc[6];
    #pragma unroll
    for (int i = 0; i < 6; ++i) {
        int s = w * 6144 + i * 1024 + l * 16;
        int n = s >> 7, c = ((s >> 4) & 7) ^ (n & 7);
        wSrc[i] = wt + (size_t)n * 1024 + c * 8;
    }

#define QKV_DMA_W(K0, BI) do { \
    _Pragma("unroll") for (int i_ = 0; i_ < 6; ++i_) \
        __builtin_amdgcn_global_load_lds( \
            (const __attribute__((address_space(1))) void*)(wSrc[i_] + (K0)), \
            (__attribute__((address_space(3))) void*)(smem + 8192 + (BI) * 24576 + w * 6144 + i_ * 1024), \
            16, 0, 0); \
} while (0)

#define QKV_LOAD_X(K0) do { \
    _Pragma("unroll") for (int i_ = 0; i_ < 2; ++i_) { int idx4 = t + 256 * i_; int r_ = idx4 >> 4, c4 = idx4 & 15; \
        xr[i_] = *(const float4*)&x[(size_t)(m0 + r_) * 1024 + (K0) + c4 * 4]; } \
} while (0)

#define QKV_STORE_X(BI) do { \
    char* xb_ = smem + (BI) * 4096; \
    _Pragma("unroll") for (int i_ = 0; i_ < 2; ++i_) { int idx4 = t + 256 * i_; int r_ = idx4 >> 4, c4 = idx4 & 15; \
        ux2 u_; u_[0] = cvtpk(xr[i_].x, xr[i_].y); u_[1] = cvtpk(xr[i_].z, xr[i_].w); \
        *(ux2*)(xb_ + ((r_ * 128 + c4 * 8) ^ ((r_ & 7) << 4))) = u_; } \
} while (0)

    QKV_LOAD_X(0); QKV_STORE_X(0); QKV_DMA_W(0, 0);
    __syncthreads();

    for (int ch = 0; ch < 16; ++ch) {
        if (ch + 1 < 16) { QKV_DMA_W((ch + 1) * 64, (ch + 1) & 1); QKV_LOAD_X((ch + 1) * 64); }
        char* xb = smem + (ch & 1) * 4096;
        char* wb = smem + 8192 + (ch & 1) * 24576;
        const int arow = rh + li;
        #pragma unroll
        for (int kk = 0; kk < 2; ++kk) {
            bfx8 af = *(bfx8*)(xb + ((arow * 128 + kk * 64 + g * 16) ^ ((arow & 7) << 4)));
            #pragma unroll
            for (int nb = 0; nb < 6; ++nb) {
                int nrow = (nb0 + nb) * 16 + li;
                bfx8 bf = *(bfx8*)(wb + ((nrow * 128 + kk * 64 + g * 16) ^ ((nrow & 7) << 4)));
                acc[nb] = __builtin_amdgcn_mfma_f32_16x16x32_bf16(af, bf, acc[nb], 0, 0, 0);
            }
        }
        if (ch + 1 < 16) QKV_STORE_X((ch + 1) & 1);
        __syncthreads();
    }

    const int mrow = m0 + rh + g * 4;
    #pragma unroll
    for (int nb = 0; nb < 6; ++nb) {
        const int nbg = nb0 + nb;
        if (nbg < 4) {
            #pragma unroll
            for (int r = 0; r < 4; ++r)
                qb[(size_t)(mrow + r) * 64 + nbg * 16 + li] = f2bf(acc[nb][r]);
        } else if (nbg < 8) {
            #pragma unroll
            for (int r = 0; r < 4; ++r)
                kb[(size_t)(mrow + r) * 64 + (nbg - 4) * 16 + li] = f2bf(acc[nb][r]);
        }
    }

    __syncthreads();
    unsigned short* Vt = (unsigned short*)smem;      // [64 d][40] padded
    #pragma unroll
    for (int nb = 0; nb < 6; ++nb) {
        const int nbg = nb0 + nb;
        if (nbg >= 8) {
            #pragma unroll
            for (int r = 0; r < 4; ++r)   // perm: u=16h+4g+r -> g*8+4h+r  (h = rh/16)
                Vt[((nbg - 8) * 16 + li) * 40 + g * 8 + (rh >> 2) + r] = f2bf(acc[nb][r]);
        }
    }
    __syncthreads();
    const int bb = m0 >> 12, mt = m0 & 4095;
    {
        int d = t >> 2, c = t & 3;
        *(bfx8*)&vt[((size_t)(bb * 64 + d)) * 4096 + mt + c * 8] = *(bfx8*)&Vt[d * 40 + c * 8];
    }
}

// ---------- attention: R12 + XCD-affinity swizzle (b from XCD; batch L2-resident) ----------
// grid 1152. XCD = bid%8 (HW heuristic): b=(bx&7)>>1 -> each XCD pair serves one batch.
// j = ((bx>>3)<<1)|(bx&1) in [0,288): heavy-first order preserved within batch.
__global__ __launch_bounds__(256, 4) void attn_mfma(
    const unsigned short* __restrict__ qb, const unsigned short* __restrict__ kb,
    const unsigned short* __restrict__ vt,
    unsigned short* __restrict__ pO, float* __restrict__ pml)
{
    __shared__ alignas(16) char smem[34816]; // K@0,8192 V@16384,24576 | epi: Osh@0 32KB, lsh@32768
    const int t = threadIdx.x;
    const int w = t >> 6, l = t & 63, g = l >> 4, li = l & 15;
    const int bx = blockIdx.x;

    const int b = (bx & 7) >> 1;              // XCD-affinity: batch = XCD pair
    const int j = ((bx >> 3) << 1) | (bx & 1);  // 0..287, heavy-first preserved
    int qt, seg, nch;
    if (j < 224) {                            // full blocks (nch=8), groups a=1..7
        int a = 1;
        #pragma unroll
        for (int aa = 2; aa <= 7; ++aa) if (j >= 4 * aa * (aa - 1)) a = aa;
        const int local = j - 4 * a * (a - 1);
        qt = 8 * a + local / a;
        seg = local % a;
        nch = 8;
    } else {                                  // diagonal blocks, heavy first
        const int jd = j - 224;               // 0..63
        const int r = 7 - (jd >> 3);
        const int a = jd & 7;
        qt = 8 * a + r; seg = a; nch = r + 1;
    }
    const int qbase = qt * 64;
    const int kvb = seg * 512;
    const int qsub = w & 1, par = w >> 1;
    const int qmax_w = qbase + qsub * 32 + 31;
    const int aq = qt >> 3, rq = qt & 7;
    const int slot = b * 288 + (aq + 1) * (4 * aq + rq) + seg;

    const unsigned short* Qg = qb + (size_t)b * 4096 * 64;
    const unsigned short* Kg = kb + (size_t)b * 4096 * 64;
    const unsigned short* Vg = vt + (size_t)b * 64 * 4096;

    // per-lane inverse-swizzled K/V sources (T21 pattern)
    const unsigned short* kSrc[2];
    const unsigned short* vSrc[2];
    #pragma unroll
    for (int i = 0; i < 2; ++i) {
        int s = w * 2048 + i * 1024 + l * 16;
        int r = s >> 7, c = ((s >> 4) & 7) ^ (r & 7);
        kSrc[i] = Kg + (size_t)r * 64 + c * 8;
        vSrc[i] = Vg + (size_t)r * 4096 + c * 8;
    }

#define ATT_DMA(CB, BI) do { \
    _Pragma("unroll") for (int i_ = 0; i_ < 2; ++i_) { \
        __builtin_amdgcn_global_load_lds( \
            (const __attribute__((address_space(1))) void*)(kSrc[i_] + (size_t)(CB) * 64), \
            (__attribute__((address_space(3))) void*)(smem + (BI) * 8192 + w * 2048 + i_ * 1024), 16, 0, 0); \
        __builtin_amdgcn_global_load_lds( \
            (const __attribute__((address_space(1))) void*)(vSrc[i_] + (CB)), \
            (__attribute__((address_space(3))) void*)(smem + 16384 + (BI) * 8192 + w * 2048 + i_ * 1024), 16, 0, 0); } \
} while (0)

    // Q fragments direct from global (L2-resident)
    bfx8 qf[2][2];
    #pragma unroll
    for (int f = 0; f < 2; ++f)
        #pragma unroll
        for (int h = 0; h < 2; ++h)
            qf[f][h] = *(const bfx8*)&Qg[(size_t)(qbase + qsub * 32 + f * 16 + li) * 64 + h * 32 + g * 8];

    // depth-2 prefetch prologue
    ATT_DMA(kvb, 0);
    if (nch > 1) ATT_DMA(kvb + 64, 1);

    fx4 o[4][2];
    #pragma unroll
    for (int i = 0; i < 4; ++i)
        #pragma unroll
        for (int f = 0; f < 2; ++f) o[i][f] = (fx4){0.f, 0.f, 0.f, 0.f};
    float lsum[2] = {0.f, 0.f};

    for (int ch = 0; ch < nch; ++ch) {
        // wait for OWN chunk-ch DMA only; chunk-(ch+1) loads stay in flight (T4)
        if (ch < nch - 1) { asm volatile("s_waitcnt vmcnt(4)" ::: "memory"); }
        else              { asm volatile("s_waitcnt vmcnt(0)" ::: "memory"); }
        __builtin_amdgcn_sched_barrier(0);
        __builtin_amdgcn_s_barrier();            // all waves' chunk-ch data landed
        asm volatile("" ::: "memory");

        char* ks = smem + (ch & 1) * 8192;
        char* vs = smem + 16384 + (ch & 1) * 8192;
        const int cb = kvb + (ch << 6);
        const int sub = cb + par * 32;
        if (sub <= qmax_w) {                     // wave-uniform causal skip
            fx4 s[2][2];
            #pragma unroll
            for (int st = 0; st < 2; ++st)
                #pragma unroll
                for (int f = 0; f < 2; ++f) s[st][f] = (fx4){0.f, 0.f, 0.f, 0.f};
            __builtin_amdgcn_s_setprio(1);
            #pragma unroll
            for (int st = 0; st < 2; ++st) {
                const int krow = par * 32 + st * 16 + li;
                const int sw = (krow & 7) << 4;
                bfx8 kf0 = *(bfx8*)(ks + ((krow * 128 + g * 16) ^ sw));
                bfx8 kf1 = *(bfx8*)(ks + ((krow * 128 + 64 + g * 16) ^ sw));
                #pragma unroll
                for (int f = 0; f < 2; ++f) {
                    s[st][f] = __builtin_amdgcn_mfma_f32_16x16x32_bf16(kf0, qf[f][0], s[st][f], 0, 0, 0);
                    s[st][f] = __builtin_amdgcn_mfma_f32_16x16x32_bf16(kf1, qf[f][1], s[st][f], 0, 0, 0);
                }
            }
            __builtin_amdgcn_s_setprio(0);

            // fixed-max softmax: P = exp2(s); pack via v_cvt_pk_bf16_f32
            bfx8 pf[2];
            #pragma unroll
            for (int f = 0; f < 2; ++f) {
                const int qmin_f = qbase + qsub * 32 + f * 16;
                float p[8];
                if (sub + 31 > qmin_f) {           // diagonal: apply causal mask
                    #pragma unroll
                    for (int st = 0; st < 2; ++st)
                        #pragma unroll
                        for (int rr = 0; rr < 4; ++rr) {
                            int kv = sub + st * 16 + 4 * g + rr;
                            p[st * 4 + rr] = (kv <= qmin_f + li) ? s[st][f][rr] : -1e30f;
                        }
                } else {
                    #pragma unroll
                    for (int st = 0; st < 2; ++st)
                        #pragma unroll
                        for (int rr = 0; rr < 4; ++rr) p[st * 4 + rr] = s[st][f][rr];
                }
                #pragma unroll
                for (int e = 0; e < 8; ++e) p[e] = exp2f(p[e]);
                lsum[f] += ((p[0]+p[1])+(p[2]+p[3])) + ((p[4]+p[5])+(p[6]+p[7]));
                ux4v pu;
                pu[0] = cvtpk(p[0], p[1]); pu[1] = cvtpk(p[2], p[3]);
                pu[2] = cvtpk(p[4], p[5]); pu[3] = cvtpk(p[6], p[7]);
                pf[f] = __builtin_bit_cast(bfx8, pu);
            }

            __builtin_amdgcn_s_setprio(1);
            #pragma unroll
            for (int dblk = 0; dblk < 4; ++dblk) {
                const int dr = dblk * 16 + li;
                // perm-baked V: one contiguous bfx8 = the exact PV A-fragment
                bfx8 vf = *(bfx8*)(vs + ((dr * 128 + par * 64 + g * 16) ^ ((dr & 7) << 4)));
                #pragma unroll
                for (int f = 0; f < 2; ++f)
                    o[dblk][f] = __builtin_amdgcn_mfma_f32_16x16x32_bf16(vf, pf[f], o[dblk][f], 0, 0, 0);
            }
            __builtin_amdgcn_s_setprio(0);
        }

        __builtin_amdgcn_s_barrier();            // all waves done reading buf[ch&1]
        asm volatile("" ::: "memory");
        if (ch + 2 < nch) ATT_DMA(kvb + ((ch + 2) << 6), ch & 1);  // refill freed buffer
    }
    asm volatile("" ::: "memory");

    // ---- epilogue: sum par pairs, write partial (l, O') ----
    float* Osh = (float*)smem;                 // [2 par][64 q][64 d] fp32 = 32KB
    float* lsh = (float*)(smem + 32768);       // [4 w][2 f][4 g][16 li]
    #pragma unroll
    for (int dblk = 0; dblk < 4; ++dblk)
        #pragma unroll
        for (int f = 0; f < 2; ++f)
            #pragma unroll
            for (int r = 0; r < 4; ++r)
                Osh[(par * 64 + qsub * 32 + f * 16 + li) * 64 + dblk * 16 + g * 4 + r] = o[dblk][f][r];
    #pragma unroll
    for (int f = 0; f < 2; ++f)
        lsh[((w * 2 + f) * 4 + g) * 16 + li] = lsum[f];
    __syncthreads();

    {
        const int q = t >> 2, dg = t & 3;
        const int A = (q >> 5), Bw = A + 2, fq = (q >> 4) & 1, liq = q & 15;
        float L = 0.f;
        #pragma unroll
        for (int gg2 = 0; gg2 < 4; ++gg2)
            L += lsh[((A * 2 + fq) * 4 + gg2) * 16 + liq] + lsh[((Bw * 2 + fq) * 4 + gg2) * 16 + liq];
        const float* OA = &Osh[q * 64 + dg * 16];
        const float* OB = &Osh[(64 + q) * 64 + dg * 16];
        ux4v u1, u2;
        u1[0] = cvtpk(OA[0] + OB[0],  OA[1] + OB[1]);
        u1[1] = cvtpk(OA[2] + OB[2],  OA[3] + OB[3]);
        u1[2] = cvtpk(OA[4] + OB[4],  OA[5] + OB[5]);
        u1[3] = cvtpk(OA[6] + OB[6],  OA[7] + OB[7]);
        u2[0] = cvtpk(OA[8] + OB[8],  OA[9] + OB[9]);
        u2[1] = cvtpk(OA[10] + OB[10], OA[11] + OB[11]);
        u2[2] = cvtpk(OA[12] + OB[12], OA[13] + OB[13]);
        u2[3] = cvtpk(OA[14] + OB[14], OA[15] + OB[15]);
        unsigned short* dst = pO + (size_t)slot * 4096 + q * 64 + dg * 16;
        *(bfx8*)&dst[0] = __builtin_bit_cast(bfx8, u1);
        *(bfx8*)&dst[8] = __builtin_bit_cast(bfx8, u2);
        if (dg == 0) pml[(size_t)slot * 64 + q] = L;
    }
}

// ---------- merge: sum up to 8 segment partials, normalize, write out ----------
__global__ __launch_bounds__(256) void attn_merge(
    const unsigned short* __restrict__ pO, const float* __restrict__ pml,
    float* __restrict__ out)
{
    const int b = blockIdx.x & 3, qt = blockIdx.x >> 2;   // qt 0..63
    const int a = qt >> 3, r = qt & 7;
    const int nseg = a + 1;
    const int slot0 = b * 288 + (a + 1) * (4 * a + r);
    const int t = threadIdx.x;
    const int q = t >> 2, dg = t & 3;

    float L = 0.f;
    float acc[16];
    #pragma unroll
    for (int jj = 0; jj < 16; ++jj) acc[jj] = 0.f;
    #pragma unroll
    for (int s = 0; s < 8; ++s) {
        if (s < nseg) {
            L += pml[(size_t)(slot0 + s) * 64 + q];
            const unsigned short* src = pO + (size_t)(slot0 + s) * 4096 + q * 64 + dg * 16;
            bfx8 v0 = *(const bfx8*)&src[0];
            bfx8 v1 = *(const bfx8*)&src[8];
            #pragma unroll
            for (int jj = 0; jj < 8; ++jj) acc[jj]     += bf2f((unsigned short)v0[jj]);
            #pragma unroll
            for (int jj = 0; jj < 8; ++jj) acc[8 + jj] += bf2f((unsigned short)v1[jj]);
        }
    }
    const float inv = 1.f / L;
    float* orow = out + ((size_t)b * 4096 + qt * 64 + q) * 64 + dg * 16;
    #pragma unroll
    for (int v4 = 0; v4 < 4; ++v4) {
        float4 rr;
        rr.x = acc[v4 * 4 + 0] * inv; rr.y = acc[v4 * 4 + 1] * inv;
        rr.z = acc[v4 * 4 + 2] * inv; rr.w = acc[v4 * 4 + 3] * inv;
        *(float4*)&orow[v4 * 4] = rr;
    }
}

extern "C" void kernel_launch(void* const* d_in, const int* in_sizes, int n_in,
                              void* d_out, int out_size, void* d_ws, size_t ws_size,
                              hipStream_t stream)
{
    // setup_inputs order: x, Wk, Wq, Wv
    const float* x  = (const float*)d_in[0];
    const float* Wk = (const float*)d_in[1];
    const float* Wq = (const float*)d_in[2];
    const float* Wv = (const float*)d_in[3];
    float* outp = (float*)d_out;

    char* ws = (char*)d_ws;
    unsigned short* qbuf = (unsigned short*)(ws);                    // 2MB
    unsigned short* kbuf = (unsigned short*)(ws + 2*1024*1024);      // 2MB
    unsigned short* vtb  = (unsigned short*)(ws + 4*1024*1024);      // 2MB (V^T, perm-baked)
    unsigned short* wtb  = (unsigned short*)(ws + 6*1024*1024);      // 384KB (W^T)
    unsigned short* pO   = (unsigned short*)(ws + 7*1024*1024);      // 1152*8KB = 9MB
    float*          pml  = (float*)(ws + 16*1024*1024 + 512*1024);   // 1152*256B = 288KB

    wt_prep<<<dim3(16, 3), 256, 0, stream>>>(Wq, Wk, Wv, wtb);
    qkv_mfma<<<512, 256, 0, stream>>>(x, wtb, qbuf, kbuf, vtb);
    attn_mfma<<<1152, 256, 0, stream>>>(qbuf, kbuf, vtb, pO, pml);
    attn_merge<<<256, 256, 0, stream>>>(pO, pml, outp);
}